// Round 5
// baseline (521.696 us; speedup 1.0000x reference)
//
#include <hip/hip_runtime.h>

// out[N,256] = concat( x[N,128] @ Wx[128,128] + bx,
//                      segsum(edge_attr by src)[N,32] @ We[32,128] + be )
//
// Pipeline:
//   binA:  bucket packed (edge_id<<8 | node&255) by src>>8 (256-node buckets)
//   gather: per bucket, stream segment -> ds_add_f32 into swizzled LDS agg
//           -> coalesced bf16 flush (no CSR, no global scatter)
//   gemm:  MFMA bf16 16x16x32, weights in swizzled LDS, A-frags from global,
//          no per-tile barriers.

#define BSHIFT    8
#define BSIZE     256
#define NBMAX     512
#define SEG_CAP   6144    // pairs per bucket (mean ~4092, +32 sigma)
#define CHUNK_A   8192
#define SPILL_CAP 65536

typedef short bf16x8 __attribute__((ext_vector_type(8)));
typedef float f32x4  __attribute__((ext_vector_type(4)));

__device__ __forceinline__ short f2bf(float f) {
    union { float f; unsigned u; } c; c.f = f;
    unsigned u = c.u;
    u += 0x7FFF + ((u >> 16) & 1);          // round-to-nearest-even
    return (short)(u >> 16);
}

// ---------- Pass A: bucket edges (packed 4B pairs) ----------
__global__ __launch_bounds__(256) void binA_kernel(
    const int* __restrict__ src, int E, int nb,
    unsigned* __restrict__ segs, int* __restrict__ gcnt,
    int2* __restrict__ spill, int* __restrict__ spillcnt)
{
    __shared__ unsigned pool[CHUNK_A];      // 32 KB
    __shared__ int hist[NBMAX];
    __shared__ int offs[NBMAX];
    __shared__ int lcur[NBMAX];
    __shared__ int gbase[NBMAX];
    __shared__ int gallow[NBMAX];
    __shared__ int wsum[4];

    int tid = threadIdx.x;
    int base = blockIdx.x * CHUNK_A;

    for (int i = tid; i < NBMAX; i += 256) hist[i] = 0;
    __syncthreads();

    for (int i = tid; i < CHUNK_A; i += 256) {
        int e = base + i;
        if (e < E) atomicAdd(&hist[src[e] >> BSHIFT], 1);
    }
    __syncthreads();

    // block exclusive scan: each thread owns buckets 2t, 2t+1
    {
        int t2 = tid * 2;
        int c0 = (t2     < nb) ? hist[t2]     : 0;
        int c1 = (t2 + 1 < nb) ? hist[t2 + 1] : 0;
        int s = c0 + c1;
        int lane = tid & 63, wid = tid >> 6;
        int ws = s;
        #pragma unroll
        for (int d = 1; d < 64; d <<= 1) {
            int t = __shfl_up(ws, d);
            if (lane >= d) ws += t;
        }
        if (lane == 63) wsum[wid] = ws;
        __syncthreads();
        int woff = 0;
        #pragma unroll
        for (int w = 0; w < 4; ++w) if (w < wid) woff += wsum[w];
        int ex = woff + ws - s;
        if (t2 < nb)     { offs[t2] = ex;          lcur[t2] = ex; }
        if (t2 + 1 < nb) { offs[t2 + 1] = ex + c0; lcur[t2 + 1] = ex + c0; }
    }
    __syncthreads();

    // reserve global segment space
    {
        int t2 = tid * 2;
        #pragma unroll
        for (int u = 0; u < 2; ++u) {
            int b = t2 + u;
            if (b < nb) {
                int cnt = hist[b];
                int b0 = cnt ? atomicAdd(&gcnt[b], cnt) : 0;
                gbase[b] = b0;
                int allow = SEG_CAP - b0;
                if (allow < 0) allow = 0;
                if (allow > cnt) allow = cnt;
                gallow[b] = allow;
            }
        }
    }
    __syncthreads();

    // place packed pairs into LDS pool grouped by bucket
    for (int i = tid; i < CHUNK_A; i += 256) {
        int e = base + i;
        if (e < E) {
            int s = src[e];
            int b = s >> BSHIFT;
            int p = atomicAdd(&lcur[b], 1);
            pool[p] = ((unsigned)e << BSHIFT) | (unsigned)(s & (BSIZE - 1));
        }
    }
    __syncthreads();

    // coalesced flush
    int wid = tid >> 6, lane = tid & 63;
    for (int b = wid; b < nb; b += 4) {
        int cnt = hist[b];
        int off = offs[b];
        int allow = gallow[b];
        unsigned* dst = segs + (size_t)b * SEG_CAP + gbase[b];
        for (int i = lane; i < allow; i += 64)
            dst[i] = pool[off + i];
        int excess = cnt - allow;
        if (excess > 0) {                 // never in practice
            int sb;
            if (lane == 0) sb = atomicAdd(spillcnt, excess);
            sb = __shfl(sb, 0);
            for (int i = lane; i < excess; i += 64) {
                int sp = sb + i;
                if (sp < SPILL_CAP) {
                    unsigned pv = pool[off + allow + i];
                    spill[sp] = make_int2((int)(pv >> BSHIFT),
                                          (b << BSHIFT) | (int)(pv & (BSIZE - 1)));
                }
            }
        }
    }
}

// ---------- gather: LDS float-atomic accumulation, bf16 flush ----------
__global__ __launch_bounds__(256) void gather_kernel(
    const unsigned* __restrict__ segs, const int* __restrict__ gcnt,
    const int2* __restrict__ spill, const int* __restrict__ spillcnt,
    const float4* __restrict__ ea4, unsigned short* __restrict__ aggbf, int N)
{
    __shared__ float sagg[BSIZE * 32];      // 32 KB, XOR-swizzled columns

    int tid = threadIdx.x;
    int b = blockIdx.x;
    int node0 = b << BSHIFT;

    for (int i = tid; i < BSIZE * 32; i += 256) sagg[i] = 0.f;
    __syncthreads();

    int segn = gcnt[b]; if (segn > SEG_CAP) segn = SEG_CAP;
    const unsigned* seg = segs + (size_t)b * SEG_CAP;

    int g = tid >> 3, q = tid & 7;          // 32 groups of 8 threads
    int cb = q * 4;

    int i = g;
    for (; i + 32 < segn; i += 64) {        // 2-way unroll for MLP
        unsigned pe0 = seg[i];
        unsigned pe1 = seg[i + 32];
        float4 v0 = ea4[(size_t)(pe0 >> BSHIFT) * 8 + q];
        float4 v1 = ea4[(size_t)(pe1 >> BSHIFT) * 8 + q];
        int d0 = pe0 & (BSIZE - 1), sw0 = (d0 & 7) << 2;
        int d1 = pe1 & (BSIZE - 1), sw1 = (d1 & 7) << 2;
        atomicAdd(&sagg[d0 * 32 + ((cb + 0) ^ sw0)], v0.x);
        atomicAdd(&sagg[d0 * 32 + ((cb + 1) ^ sw0)], v0.y);
        atomicAdd(&sagg[d0 * 32 + ((cb + 2) ^ sw0)], v0.z);
        atomicAdd(&sagg[d0 * 32 + ((cb + 3) ^ sw0)], v0.w);
        atomicAdd(&sagg[d1 * 32 + ((cb + 0) ^ sw1)], v1.x);
        atomicAdd(&sagg[d1 * 32 + ((cb + 1) ^ sw1)], v1.y);
        atomicAdd(&sagg[d1 * 32 + ((cb + 2) ^ sw1)], v1.z);
        atomicAdd(&sagg[d1 * 32 + ((cb + 3) ^ sw1)], v1.w);
    }
    for (; i < segn; i += 32) {
        unsigned pe = seg[i];
        float4 v = ea4[(size_t)(pe >> BSHIFT) * 8 + q];
        int d = pe & (BSIZE - 1), sw = (d & 7) << 2;
        atomicAdd(&sagg[d * 32 + ((cb + 0) ^ sw)], v.x);
        atomicAdd(&sagg[d * 32 + ((cb + 1) ^ sw)], v.y);
        atomicAdd(&sagg[d * 32 + ((cb + 2) ^ sw)], v.z);
        atomicAdd(&sagg[d * 32 + ((cb + 3) ^ sw)], v.w);
    }

    // spill (never in practice)
    int nsp = *spillcnt; if (nsp > SPILL_CAP) nsp = SPILL_CAP;
    for (int k = tid; k < nsp; k += 256) {
        int2 p = spill[k];
        if ((p.y >> BSHIFT) == b) {
            int d = p.y & (BSIZE - 1), sw = (d & 7) << 2;
            for (int j = 0; j < 8; ++j) {
                float4 v = ea4[(size_t)p.x * 8 + j];
                atomicAdd(&sagg[d * 32 + ((j * 4 + 0) ^ sw)], v.x);
                atomicAdd(&sagg[d * 32 + ((j * 4 + 1) ^ sw)], v.y);
                atomicAdd(&sagg[d * 32 + ((j * 4 + 2) ^ sw)], v.z);
                atomicAdd(&sagg[d * 32 + ((j * 4 + 3) ^ sw)], v.w);
            }
        }
    }
    __syncthreads();

    // bf16 flush, coalesced
    for (int k = tid; k < BSIZE * 32; k += 256) {
        int d = k >> 5, c = k & 31;
        int node = node0 + d;
        if (node < N)
            aggbf[(size_t)node * 32 + c] = (unsigned short)f2bf(sagg[d * 32 + (c ^ ((d & 7) << 2))]);
    }
}

// ---------- fallback: atomic scatter + convert ----------
__global__ __launch_bounds__(256) void scatter_kernel(
    const float4* __restrict__ ea4, const int* __restrict__ src,
    float* __restrict__ agg, int nquads)
{
    int t = blockIdx.x * blockDim.x + threadIdx.x;
    if (t >= nquads) return;
    int e = t >> 3, q = t & 7;
    float4 v = ea4[t];
    int node = src[e];
    float* dst = agg + (size_t)node * 32 + q * 4;
    atomicAdd(dst + 0, v.x); atomicAdd(dst + 1, v.y);
    atomicAdd(dst + 2, v.z); atomicAdd(dst + 3, v.w);
}

__global__ __launch_bounds__(256) void cvt_kernel(
    const float* __restrict__ agg, unsigned short* __restrict__ aggbf, int n)
{
    int t = blockIdx.x * blockDim.x + threadIdx.x;
    if (t < n) aggbf[t] = (unsigned short)f2bf(agg[t]);
}

// ---------- MFMA bf16 fused dual-GEMM ----------
// 512 threads = 8 waves; wave w computes rows [t*128 + w*16, +16) x 256 cols.
// Wx^T, We^T staged once per block in swizzled LDS; x/agg A-frags from global.
__global__ __launch_bounds__(512, 4) void mfma_gemm(
    const float* __restrict__ x, const unsigned short* __restrict__ aggbf,
    const float* __restrict__ Wx, const float* __restrict__ bx,
    const float* __restrict__ We, const float* __restrict__ be,
    float* __restrict__ out, int N, int ntiles)
{
    __shared__ char sWxT[128 * 256];   // [j][k] bf16, swizzled: 32 KB
    __shared__ char sWeT[128 * 64];    // [j][k] bf16, swizzled:  8 KB

    int tid = threadIdx.x;
    int lane = tid & 63, w = tid >> 6;
    int col = lane & 15, m = lane >> 4;

    // stage transposed weights (once per block)
    for (int i = tid; i < 128 * 128; i += 512) {
        int k = i >> 7, j = i & 127;
        *(short*)(sWxT + j * 256 + ((k * 2) ^ ((j & 7) << 4))) = f2bf(Wx[i]);
    }
    for (int i = tid; i < 32 * 128; i += 512) {
        int k = i >> 7, j = i & 127;
        *(short*)(sWeT + j * 64 + ((k * 2) ^ ((j & 3) << 4))) = f2bf(We[i]);
    }
    float bxv[8], bev[8];
    #pragma unroll
    for (int ct = 0; ct < 8; ++ct) {
        bxv[ct] = bx[ct * 16 + col];
        bev[ct] = be[ct * 16 + col];
    }
    __syncthreads();

    for (int t = blockIdx.x; t < ntiles; t += gridDim.x) {
        int rbase = (t << 7) + (w << 4);
        int lrow = rbase + col;                 // A-frag row for this lane
        bool rok = lrow < N;

        // x A-frags (kk=0..3): 16 rows x 128B segments, each element read once
        const float* xr = x + (size_t)lrow * 128 + m * 8;
        bf16x8 ax[4];
        #pragma unroll
        for (int kk = 0; kk < 4; ++kk) {
            float4 p0 = {0.f, 0.f, 0.f, 0.f}, p1 = {0.f, 0.f, 0.f, 0.f};
            if (rok) {
                p0 = *(const float4*)(xr + kk * 32);
                p1 = *(const float4*)(xr + kk * 32 + 4);
            }
            bf16x8 a;
            a[0] = f2bf(p0.x); a[1] = f2bf(p0.y); a[2] = f2bf(p0.z); a[3] = f2bf(p0.w);
            a[4] = f2bf(p1.x); a[5] = f2bf(p1.y); a[6] = f2bf(p1.z); a[7] = f2bf(p1.w);
            ax[kk] = a;
        }
        // agg A-frag (bf16 direct, 16B load)
        bf16x8 aa = {0, 0, 0, 0, 0, 0, 0, 0};
        if (rok) aa = *(const bf16x8*)(aggbf + (size_t)lrow * 32 + m * 8);

        f32x4 acc[16];
        #pragma unroll
        for (int ct = 0; ct < 8; ++ct) {
            acc[ct]     = (f32x4){bxv[ct], bxv[ct], bxv[ct], bxv[ct]};
            acc[8 + ct] = (f32x4){bev[ct], bev[ct], bev[ct], bev[ct]};
        }

        #pragma unroll
        for (int ct = 0; ct < 8; ++ct) {
            const char* brow = sWxT + (ct * 16 + col) * 256;
            int swz = (col & 7) << 4;
            #pragma unroll
            for (int kk = 0; kk < 4; ++kk) {
                bf16x8 bfrag = *(const bf16x8*)(brow + ((kk * 64 + m * 16) ^ swz));
                acc[ct] = __builtin_amdgcn_mfma_f32_16x16x32_bf16(ax[kk], bfrag, acc[ct], 0, 0, 0);
            }
            bf16x8 bwe = *(const bf16x8*)(sWeT + (ct * 16 + col) * 64 + ((m * 16) ^ ((col & 3) << 4)));
            acc[8 + ct] = __builtin_amdgcn_mfma_f32_16x16x32_bf16(aa, bwe, acc[8 + ct], 0, 0, 0);
        }

        // store: C/D row = m*4 + r, col = col (+16*ct)
        int srow = rbase + m * 4;
        #pragma unroll
        for (int r = 0; r < 4; ++r) {
            if (srow + r < N) {
                float* orow = out + (size_t)(srow + r) * 256 + col;
                #pragma unroll
                for (int ct = 0; ct < 8; ++ct) {
                    orow[ct * 16]       = acc[ct][r];
                    orow[128 + ct * 16] = acc[8 + ct][r];
                }
            }
        }
    }
}

extern "C" void kernel_launch(void* const* d_in, const int* in_sizes, int n_in,
                              void* d_out, int out_size, void* d_ws, size_t ws_size,
                              hipStream_t stream) {
    const float* x          = (const float*)d_in[0];
    const int*   edge_index = (const int*)d_in[1];   // [2,E] flat; row 0 = src
    const float* edge_attr  = (const float*)d_in[2];
    const float* Wx         = (const float*)d_in[3];
    const float* bx         = (const float*)d_in[4];
    const float* We         = (const float*)d_in[5];
    const float* be         = (const float*)d_in[6];
    float* out = (float*)d_out;

    int N = in_sizes[0] / 128;
    int E = in_sizes[2] / 32;
    int nb = (N + BSIZE - 1) >> BSHIFT;
    int ntiles = (N + 127) >> 7;

    char* ws = (char*)d_ws;
    size_t aggbfBytes = ((size_t)N * 32 * 2 + 255) & ~255ull;
    size_t segsBytes  = ((size_t)nb * SEG_CAP * 4 + 255) & ~255ull;
    size_t gcntBytes  = ((size_t)(nb + 1) * 4 + 255) & ~255ull;
    size_t spillBytes = (size_t)SPILL_CAP * 8;
    size_t need = aggbfBytes + segsBytes + gcntBytes + spillBytes;

    unsigned short* aggbf = (unsigned short*)ws;

    if (ws_size >= need && nb <= NBMAX) {
        unsigned* segs  = (unsigned*)(ws + aggbfBytes);
        int* gcnt       = (int*)(ws + aggbfBytes + segsBytes);
        int* spillcnt   = gcnt + nb;
        int2* spill     = (int2*)(ws + aggbfBytes + segsBytes + gcntBytes);

        hipMemsetAsync(gcnt, 0, (size_t)(nb + 1) * 4, stream);
        int nblkA = (E + CHUNK_A - 1) / CHUNK_A;
        binA_kernel<<<nblkA, 256, 0, stream>>>(edge_index, E, nb, segs, gcnt, spill, spillcnt);
        gather_kernel<<<nb, 256, 0, stream>>>(segs, gcnt, spill, spillcnt,
                                              (const float4*)edge_attr, aggbf, N);
    } else {
        float* aggf = (float*)(ws + aggbfBytes);
        hipMemsetAsync(aggf, 0, (size_t)N * 32 * 4, stream);
        int nq = E * 8;
        scatter_kernel<<<(nq + 255) / 256, 256, 0, stream>>>(
            (const float4*)edge_attr, edge_index, aggf, nq);
        cvt_kernel<<<(N * 32 + 255) / 256, 256, 0, stream>>>(aggf, aggbf, N * 32);
    }

    int g = (ntiles + 1) / 2;
    mfma_gemm<<<g, 512, 0, stream>>>(x, aggbf, Wx, bx, We, be, out, N, ntiles);
}